// Round 6
// baseline (14.919 us; speedup 1.0000x reference)
//
#include <hip/hip_runtime.h>
#include <stdint.h>

#define NB   16      // NUM_BATCHES
#define K    32      // MAX_NUM_NEIGHBORS
#define R2   0.0625f // RADIUS^2 = 0.25^2, exact in f32
#define WPB  4       // waves (targets) per block
#define MAXC 256     // per-wave candidate buffer (observed max ~60; >=6 sigma)

// Single fused kernel: ONE WAVE per target.
//   bounds: wave-local 2-level sampled search. Coarse: 64 samples at stride
//           128 + ballot/popcount -> 128-wide window for lower_bound(b) and
//           lower_bound(b+1). Fine: half-wave per bound, 4 independent loads
//           per lane + ballots. ~2 load latencies total, no dependent chain,
//           no LDS, no barrier. (Fallback binary search if n != 8192.)
//   scan  : wave-uniform trip count, software-pipelined (prefetch next point
//           while compacting current). sq[j] recomputed inline from x[j] with
//           the exact numpy expression (contract off) -> bit-identical.
//           Passing keys compacted into per-wave LDS via ballot + popcount.
//   rank  : lane p ranks key p against all cnt keys (broadcast LDS reads);
//           rank < K -> scatter src index into res[rank].
//   Key = (ordered d2 bits << 32) | j  ->  uint64 ascending == (d2 asc, j asc)
//   == lax.top_k stable tie-break. FP path identical to the passing kernel.
__global__ __launch_bounds__(256) void radius_knn_fused(
    const float* __restrict__ x,
    const int* __restrict__ batch,
    int n,
    int* __restrict__ out,
    int row_stride /* = n*K */) {
#pragma clang fp contract(off)
    __shared__ uint64_t buf[WPB][MAXC];
    __shared__ int      res[WPB][K];

    const int tid  = threadIdx.x;
    const int lane = tid & 63;
    const int wid  = tid >> 6;
    const int i    = blockIdx.x * WPB + wid;   // n % WPB == 0: no early return

    const int b = batch[i];

    int s, e;
    if (n == 8192) {
        // ---- wave-local sampled bounds search ----
        // coarse: 64 samples at stride 128 (single scattered load + 2 ballots)
        const int samp = batch[lane << 7];
        const int m1 = (int)__popcll(__ballot(samp < b));
        const int m2 = (int)__popcll(__ballot(samp < b + 1));
        // fine: half 0 counts (batch < b) in window of m1,
        //       half 1 counts (batch < b+1) in window of m2.
        const int half = lane >> 5;
        const int hl   = lane & 31;
        const int mv   = half ? m2 : m1;
        const int vv   = half ? (b + 1) : b;
        const int Wv   = 128 * (mv - 1) + 1;   // negative iff mv==0 (ignored)
        const int idx0 = Wv + 4 * hl;
        uint64_t bal[4];
#pragma unroll
        for (int k = 0; k < 4; ++k) {
            const int idx = idx0 + k;
            const int idc = idx < 0 ? 0 : (idx >= n ? n - 1 : idx);
            const bool p  = (idx >= 0) && (idx < n) && (batch[idc] < vv);
            bal[k] = __ballot(p);
        }
        int cl = 0, ch = 0;
#pragma unroll
        for (int k = 0; k < 4; ++k) {
            cl += (int)__popcll(bal[k] & 0xffffffffull);
            ch += (int)__popcll(bal[k] >> 32);
        }
        s = (m1 == 0) ? 0 : (128 * (m1 - 1) + 1 + cl);
        e = (m2 == 0) ? 0 : (128 * (m2 - 1) + 1 + ch);
    } else {
        // fallback (never taken for this problem): per-wave binary search
        int lo = 0, hi = n;
        while (lo < hi) {
            int mid = (lo + hi) >> 1;
            if (batch[mid] < b) lo = mid + 1; else hi = mid;
        }
        s = lo;
        int lo2 = s, hi2 = n;
        while (lo2 < hi2) {
            int mid = (lo2 + hi2) >> 1;
            if (batch[mid] <= b) lo2 = mid + 1; else hi2 = mid;
        }
        e = lo2;
    }

    // ---- target point + its squared norm (numpy-exact: no contraction) ----
    const float xi0 = x[i * 3 + 0];
    const float xi1 = x[i * 3 + 1];
    const float xi2 = x[i * 3 + 2];
    const float q0 = xi0 * xi0, q1 = xi1 * xi1, q2 = xi2 * xi2;
    const float sqi = (q0 + q1) + q2;

    // ---- scan + ballot-compaction, software-pipelined ----
    const int range = e - s;
    const int iters = (range + 63) >> 6;
    int cbase = 0;

    int j  = s + lane;
    int jc = (j < e) ? j : s;                  // clamp for safe loads
    float y0 = x[jc * 3 + 0];
    float y1 = x[jc * 3 + 1];
    float y2 = x[jc * 3 + 2];

    for (int it = 0; it < iters; ++it) {
        // prefetch next iteration's point (clamped address is always valid)
        const int jn  = j + 64;
        const int jnc = (jn < e) ? jn : s;
        const float z0 = x[jnc * 3 + 0];
        const float z1 = x[jnc * 3 + 1];
        const float z2 = x[jnc * 3 + 2];

        // sq[j] inline, identical expression to numpy's elementwise square+sum
        float p0 = y0 * y0, p1 = y1 * y1, p2 = y2 * y2;
        float sqj = (p0 + p1) + p2;
        // sgemm-style K=3 dot: fma chain accumulating from 0.
        float dot = xi0 * y0;
        dot = fmaf(xi1, y1, dot);
        dot = fmaf(xi2, y2, dot);
        float d2 = (sqi + sqj) - 2.0f * dot;
        bool pass = (j < e) && (j != i) && (d2 <= R2);

        d2 = d2 + 0.0f;                        // normalize -0.0 -> +0.0
        uint32_t u = __float_as_uint(d2);
        u = (u & 0x80000000u) ? ~u : (u | 0x80000000u);
        uint64_t key = ((uint64_t)u << 32) | (uint32_t)jc;

        uint64_t mask = __ballot(pass);
        if (pass) {
            int off = cbase + __popcll(mask & ((1ull << lane) - 1ull));
            if (off < MAXC) buf[wid][off] = key;
        }
        cbase += (int)__popcll(mask);

        j = jn; jc = jnc; y0 = z0; y1 = z1; y2 = z2;
    }
    int cnt = cbase < MAXC ? cbase : MAXC;
    const int nsel = cnt < K ? cnt : K;

    __syncthreads();   // buf visible (uniform: every thread reaches)

    // ---- rank + scatter: lane p ranks key p against all cnt keys ----
    for (int p = lane; p < cnt; p += 64) {
        uint64_t kp = buf[wid][p];
        int r = 0;
        for (int q = 0; q < cnt; ++q)
            r += (buf[wid][q] < kp) ? 1 : 0;
        if (r < K) res[wid][r] = (int)(uint32_t)(kp & 0xffffffffu);
    }

    __syncthreads();   // res visible (uniform)

    // ---- epilogue: row 0 = src (lanes 0..31), row 1 = tgt (lanes 32..63) ----
    const long base = (long)i * K;
    if (lane < K) {
        out[base + lane] = (lane < nsel) ? res[wid][lane] : -1;
    } else {
        const int l2 = lane - K;
        out[row_stride + base + l2] = (l2 < nsel) ? i : -1;
    }
}

extern "C" void kernel_launch(void* const* d_in, const int* in_sizes, int n_in,
                              void* d_out, int out_size, void* d_ws, size_t ws_size,
                              hipStream_t stream) {
    const float* x     = (const float*)d_in[0];
    const int*   batch = (const int*)d_in[1];
    const int    n     = in_sizes[1];          // 8192
    int*         out   = (int*)d_out;
    const int row_stride = out_size / 2;       // n*K

    const int blocks = n / WPB;                // one wave per target
    radius_knn_fused<<<blocks, 256, 0, stream>>>(x, batch, n, out, row_stride);
}